// Round 13
// baseline (155.186 us; speedup 1.0000x reference)
//
#include <hip/hip_runtime.h>
#include <math.h>

// HardTripletLoss: B=4096, D=512, labels in [0,64), margin 0.5, scalar fp32 out.
// R13: R3's proven 2-barrier BK=64 loop + XOR swizzle (0 conflicts), but tiles
// split into 128x64 column-halves: 1056 blocks = 4.125/CU (~16.5 waves/CU)
// instead of 528 = 2.06/CU. Occupancy was R3's quantified deficiency.
// Finalize fused via done-counter (block-wide reduction in the last block).
//
// ws layout (floats): [0,4096)=hp, [4096,8192)=hn, [8192,12288)=norms,
//                     [12288]=done(int), [16384, +2M ushorts)=xhi (4 MB)

#define NB 4096
#define ND 512
#define NLAB 64
#define NBLK 1056  // 528 triangle tiles x 2 column-halves

typedef __attribute__((ext_vector_type(8))) short short8;
typedef __attribute__((ext_vector_type(4))) float f32x4;

__device__ __forceinline__ ushort bf16rn(float f) {
    unsigned u = __float_as_uint(f);
    u += 0x7FFF + ((u >> 16) & 1);  // round-to-nearest-even
    return (ushort)(u >> 16);
}

__device__ __forceinline__ void gload_lds16(const ushort* g, ushort* l) {
    __builtin_amdgcn_global_load_lds(
        (const __attribute__((address_space(1))) void*)g,
        (__attribute__((address_space(3))) void*)l, 16, 0, 0);
}

// One wave per row: fp32->bf16 convert + exact fp32 norm; init hp/hn; zero done.
__global__ __launch_bounds__(256) void k_prep(const float* __restrict__ x,
                                              ushort* __restrict__ xhi,
                                              float* __restrict__ norms,
                                              float* __restrict__ hp,
                                              float* __restrict__ hn,
                                              int* __restrict__ done) {
    const int wave = threadIdx.x >> 6, lane = threadIdx.x & 63;
    const int row = blockIdx.x * 4 + wave;
    const float* p = x + (size_t)row * ND + lane * 8;
    float4 v0 = *(const float4*)p;
    float4 v1 = *(const float4*)(p + 4);
    ushort h[8];
    h[0] = bf16rn(v0.x); h[1] = bf16rn(v0.y); h[2] = bf16rn(v0.z); h[3] = bf16rn(v0.w);
    h[4] = bf16rn(v1.x); h[5] = bf16rn(v1.y); h[6] = bf16rn(v1.z); h[7] = bf16rn(v1.w);
    *(uint4*)(xhi + (size_t)row * ND + lane * 8) = *(const uint4*)h;
    float s = v0.x*v0.x + v0.y*v0.y + v0.z*v0.z + v0.w*v0.w
            + v1.x*v1.x + v1.y*v1.y + v1.z*v1.z + v1.w*v1.w;
    #pragma unroll
    for (int m = 1; m < 64; m <<= 1) s += __shfl_xor(s, m);
    if (lane == 0) norms[row] = s;
    if (threadIdx.x < 4) {
        hp[blockIdx.x * 4 + threadIdx.x] = 0.0f;
        hn[blockIdx.x * 4 + threadIdx.x] = __int_as_float(0x7F800000);
    }
    if (blockIdx.x == 0 && threadIdx.x == 0) *done = 0;
}

// 128x64 output half-tile per block. 256 threads = 4 waves, each a 64x32
// quadrant (4x2 tiles of mfma_f32_16x16x32_bf16). BK=64, single-buffer LDS
// with global_load_lds(16B); XOR chunk swizzle phys = logical ^ (row&7)
// applied at the SOURCE address, un-applied at fragment reads -> 0 conflicts.
__global__ __launch_bounds__(256, 2) void k_dist(const ushort* __restrict__ xhi,
                                                 const int* __restrict__ labels,
                                                 const float* __restrict__ norms,
                                                 float* __restrict__ hp,
                                                 float* __restrict__ hn,
                                                 int* __restrict__ done,
                                                 float* __restrict__ out) {
    __shared__ ushort As[128 * 64];  // 16 KB, row stride 64 ushorts (128 B)
    __shared__ ushort Bs[64 * 64];   //  8 KB
    __shared__ int hh[NLAB];
    __shared__ int lastFlag;

    // Decode: bid -> (triangle pair, column half). Triangle over 32x32 tiles.
    const int bid = blockIdx.x;
    const int pair = bid >> 1, half = bid & 1;
    int r = (int)((65.0f - sqrtf(4225.0f - 8.0f * (float)pair)) * 0.5f);
    int base = r * 32 - (r * (r - 1)) / 2;
    if (pair < base)                { --r; base = r * 32 - (r * (r - 1)) / 2; }
    else if (pair >= base + 32 - r) { ++r; base = r * 32 - (r * (r - 1)) / 2; }
    const int rb  = r * 128;
    const int cbh = (r + (pair - base)) * 128 + half * 64;  // 64-col half

    const int tid = threadIdx.x;
    const int w = tid >> 6, lane = tid & 63;
    const int wr = (w >> 1) * 64, wc = (w & 1) * 32;  // 64x32 quadrant
    const int q = lane >> 4, fr = lane & 15;
    const int srow8 = lane >> 3;               // row within 8-row group
    const int sch = (lane & 7) ^ srow8;        // swizzled source k-chunk

    f32x4 acc[4][2];
    #pragma unroll
    for (int mi = 0; mi < 4; ++mi)
        #pragma unroll
        for (int ni = 0; ni < 2; ++ni)
            acc[mi][ni] = (f32x4){0.f, 0.f, 0.f, 0.f};

    // Staging: 192 rows total (A:128 + B:64) = 24 gload_lds16; wave w covers
    // rows [w*48, w*48+48) in 6 instrs of 8 rows (region uniform per instr).
    for (int kb = 0; kb < ND; kb += 64) {
        #pragma unroll
        for (int t = 0; t < 6; ++t) {
            const int gr = w * 48 + t * 8;  // wave-uniform
            const ushort* src = (gr < 128)
                ? xhi + (size_t)(rb + gr + srow8) * ND + kb + sch * 8
                : xhi + (size_t)(cbh + gr - 128 + srow8) * ND + kb + sch * 8;
            ushort* dst = (gr < 128) ? (As + gr * 64) : (Bs + (gr - 128) * 64);
            gload_lds16(src, dst);
        }
        __syncthreads();  // drains vmcnt -> LDS valid

        #pragma unroll
        for (int kk = 0; kk < 2; ++kk) {
            short8 a[4], b[2];
            #pragma unroll
            for (int mi = 0; mi < 4; ++mi) {
                const int R = wr + mi * 16 + fr;
                const int pc = ((kk << 2) | q) ^ (R & 7);
                a[mi] = *(const short8*)(As + R * 64 + pc * 8);
            }
            #pragma unroll
            for (int ni = 0; ni < 2; ++ni) {
                const int R = wc + ni * 16 + fr;
                const int pc = ((kk << 2) | q) ^ (R & 7);
                b[ni] = *(const short8*)(Bs + R * 64 + pc * 8);
            }
            #pragma unroll
            for (int mi = 0; mi < 4; ++mi)
                #pragma unroll
                for (int ni = 0; ni < 2; ++ni)
                    acc[mi][ni] = __builtin_amdgcn_mfma_f32_16x16x32_bf16(
                        a[mi], b[ni], acc[mi][ni], 0, 0, 0);
        }
        __syncthreads();
    }

    // Epilogue. C/D layout: col = lane&15, row = (lane>>4)*4 + reg.
    int gcol[2]; float ncol[2]; int lcol[2];
    #pragma unroll
    for (int ni = 0; ni < 2; ++ni) {
        gcol[ni] = cbh + wc + ni * 16 + fr;
        ncol[ni] = norms[gcol[ni]];
        lcol[ni] = labels[gcol[ni]];
    }
    float pmc[2], nmc[2];  // column-anchored stats
    #pragma unroll
    for (int ni = 0; ni < 2; ++ni) {
        pmc[ni] = 0.0f;
        nmc[ni] = __int_as_float(0x7F800000);
    }
    #pragma unroll
    for (int mi = 0; mi < 4; ++mi) {
        #pragma unroll
        for (int reg = 0; reg < 4; ++reg) {
            const int grow = rb + wr + mi * 16 + q * 4 + reg;
            const float nr = norms[grow];
            const int lr = labels[grow];
            float pm = 0.0f, nm = __int_as_float(0x7F800000);
            #pragma unroll
            for (int ni = 0; ni < 2; ++ni) {
                float sq = fmaxf(nr + ncol[ni] - 2.0f * acc[mi][ni][reg], 0.0f);
                float dd = sqrtf(sq);
                if (lr == lcol[ni]) {
                    if (grow != gcol[ni]) {
                        pm = fmaxf(pm, dd);
                        pmc[ni] = fmaxf(pmc[ni], dd);
                    }
                } else {
                    nm = fminf(nm, dd);
                    nmc[ni] = fminf(nmc[ni], dd);
                }
            }
            // row stats: reduce over the 16 column-lanes (lane bits 0..3)
            #pragma unroll
            for (int m = 1; m <= 8; m <<= 1) {
                pm = fmaxf(pm, __shfl_xor(pm, m));
                nm = fminf(nm, __shfl_xor(nm, m));
            }
            if (fr == 0) {
                // Nonneg floats: int compare == float compare.
                atomicMax((int*)&hp[grow], __float_as_int(pm));
                atomicMin((int*)&hn[grow], __float_as_int(nm));
            }
        }
    }
    // col stats (symmetry coverage): reduce over the 4 quad-lanes (bits 4..5).
    // Always done (half-tiles are not self-symmetric even on the diagonal;
    // diagonal duplicates are harmless for idempotent max/min).
    #pragma unroll
    for (int ni = 0; ni < 2; ++ni) {
        #pragma unroll
        for (int m = 16; m <= 32; m <<= 1) {
            pmc[ni] = fmaxf(pmc[ni], __shfl_xor(pmc[ni], m));
            nmc[ni] = fminf(nmc[ni], __shfl_xor(nmc[ni], m));
        }
        if (q == 0) {
            atomicMax((int*)&hp[gcol[ni]], __float_as_int(pmc[ni]));
            atomicMin((int*)&hn[gcol[ni]], __float_as_int(nmc[ni]));
        }
    }

    // Last-block finalize: release fence + counter; winner reduces block-wide.
    __threadfence();
    __syncthreads();  // all waves' atomics issued before the block's increment
    if (tid == 0) lastFlag = (atomicAdd(done, 1) == NBLK - 1) ? 1 : 0;
    __syncthreads();
    if (lastFlag) {
        __threadfence();  // acquire side
        if (tid < NLAB) hh[tid] = 0;
        __syncthreads();
        for (int i = tid; i < NB; i += 256) atomicAdd(&hh[labels[i]], 1);
        __syncthreads();
        float s = 0.0f;
        int c = 0;
        for (int i = tid; i < NB; i += 256) {
            const int k = hh[labels[i]];
            if (k >= 2 && k < NB) {
                float av = __hip_atomic_load(&hp[i], __ATOMIC_RELAXED, __HIP_MEMORY_SCOPE_AGENT);
                float bv = __hip_atomic_load(&hn[i], __ATOMIC_RELAXED, __HIP_MEMORY_SCOPE_AGENT);
                s += fmaxf(av - bv + 0.5f, 0.0f);
                c += 1;
            }
        }
        #pragma unroll
        for (int m = 1; m < 64; m <<= 1) {
            s += __shfl_xor(s, m);
            c += __shfl_xor(c, m);
        }
        __shared__ float sw[4];
        __shared__ int cw[4];
        if ((tid & 63) == 0) { sw[tid >> 6] = s; cw[tid >> 6] = c; }
        __syncthreads();
        if (tid == 0) {
            float S = sw[0] + sw[1] + sw[2] + sw[3];
            int   C = cw[0] + cw[1] + cw[2] + cw[3];
            out[0] = (C > 0) ? (S / (float)C) : 0.0f;
        }
    }
}

extern "C" void kernel_launch(void* const* d_in, const int* in_sizes, int n_in,
                              void* d_out, int out_size, void* d_ws, size_t ws_size,
                              hipStream_t stream) {
    const float* x      = (const float*)d_in[0];
    const int*   labels = (const int*)d_in[1];
    float* ws    = (float*)d_ws;
    float* hp    = ws;
    float* hn    = ws + NB;
    float* norms = ws + 2 * NB;
    int*   done  = (int*)(ws + 3 * NB);
    ushort* xhi  = (ushort*)(ws + 4 * NB);   // 4 MB bf16 matrix
    float* out   = (float*)d_out;

    k_prep<<<dim3(NB / 4), dim3(256), 0, stream>>>(x, xhi, norms, hp, hn, done);
    k_dist<<<dim3(NBLK), dim3(256), 0, stream>>>(xhi, labels, norms, hp, hn, done, out);
}